// Round 7
// baseline (100.979 us; speedup 1.0000x reference)
//
#include <hip/hip_runtime.h>

namespace {

constexpr int NQ = 12;
constexpr int DIM = 1 << NQ;   // 4096
constexpr int THREADS = 256;

struct c32 { float r, i; };

__device__ __forceinline__ c32 cmul(c32 a, c32 b) {
    return { fmaf(a.r, b.r, -(a.i * b.i)), fmaf(a.r, b.i, a.i * b.r) };
}

__device__ __forceinline__ float rlf(float v, int lane) {   // compile-time lane -> SGPR
    return __int_as_float(__builtin_amdgcn_readlane(__float_as_int(v), lane));
}
__device__ __forceinline__ float shf(float v, int lane) {   // runtime lane (bpermute)
    return __shfl(v, lane, 64);
}

// real-coefficient RY butterfly: 8 ops/pair, scalar (SGPR) coefficients
__device__ __forceinline__ void bfy(c32& x, c32& y, float cb, float sb) {
    const c32 a = x, b = y;
    x.r = fmaf(cb, a.r, -(sb * b.r));
    x.i = fmaf(cb, a.i, -(sb * b.i));
    y.r = fmaf(sb, a.r, cb * b.r);
    y.i = fmaf(sb, a.i, cb * b.i);
}

template<int BP>
__device__ __forceinline__ void applyRY(c32 v[16], float cb, float sb) {
    #pragma unroll
    for (int mi = 0; mi < 8; ++mi) {
        const int i0 = ((mi >> BP) << (BP + 1)) | (mi & ((1 << BP) - 1));
        bfy(v[i0], v[i0 | (1 << BP)], cb, sb);
    }
}

// ---- XOR-linear address algebra (identical to passing R5) ----
__host__ __device__ constexpr int G(int t, int k) {
    for (int i = 0; i < k; ++i) t = (t ^ (t >> 1)) & 0xFFF;
    return t;
}
__host__ __device__ constexpr int Cm(int t) {
    int lo = 0;
    if (t & 0x010) lo ^= 0x2;
    if (t & 0x020) lo ^= 0x4;
    if (t & 0x040) lo ^= 0x8;
    if (t & 0x080) lo ^= 0x6;
    if (t & 0x100) lo ^= 0xA;
    if (t & 0x200) lo ^= 0xC;
    return t ^ lo;
}
__host__ __device__ constexpr int maskE_calc() {
    int m = 0;
    for (int i = 0; i < 12; ++i) {
        int v = G(Cm(1 << i), 12), p = 0;
        while (v) { p ^= (v & 1); v >>= 1; }
        if (p) m |= (1 << i);
    }
    return m;
}
constexpr int MASKE = maskE_calc();

// per-thread diag product tree for layer 0 (identical to passing R5)
__device__ __forceinline__ void diagTree(c32 T[16], c32 C,
                                         const c32 pf0[4], const c32 pf1[4],
                                         const c32 qv[4], int sigma) {
    const c32 one = { 1.f, 0.f };
    T[0] = C;
    #pragma unroll
    for (int m = 3; m >= 0; --m) {
        const c32 qs0 = sigma ? qv[m] : one;
        const c32 qs1 = sigma ? one : qv[m];
        const c32 g00 = cmul(pf0[m], qs0);
        const c32 g01 = cmul(pf0[m], qs1);
        const c32 g10 = cmul(pf1[m], qs0);
        const c32 g11 = cmul(pf1[m], qs1);
        #pragma unroll
        for (int e = (1 << (3 - m)) - 1; e >= 0; --e) {
            const int j0 = e << (m + 1);
            const int sfxhi = __popc(e) & 1;
            const c32 ga = sfxhi ? g01 : g00;
            const c32 gb = sfxhi ? g10 : g11;
            T[j0 | (1 << m)] = cmul(T[j0], gb);
            T[j0]            = cmul(T[j0], ga);
        }
    }
}

__global__ __launch_bounds__(THREADS, 5)
void qcirc_kernel(const float* __restrict__ x, const float* __restrict__ thetas,
                  float* __restrict__ out) {
    __shared__ alignas(16) float2 amp[DIM];   // exactly 32 KB -> 5 blocks/CU
    float4* a4 = reinterpret_cast<float4*>(amp);

    const int tid = threadIdx.x;
    const int ln  = tid & 63;
    const int b = blockIdx.x;

    // ---- per-lane fused gate build + P*Ry*Q decomposition (lane g = gate g) ----
    const float xv = x[b];
    const float x1 = asinf(xv);
    const float x2 = acosf(xv * xv);
    const float cyf = cosf(0.5f * x1), syf = sinf(0.5f * x1);
    const float czf = cosf(0.5f * x2), szf = sinf(0.5f * x2);
    const c32 M00 = {  czf * cyf, -szf * cyf };
    const c32 M01 = { -czf * syf,  szf * syf };
    const c32 M10 = {  czf * syf,  szf * syf };
    const c32 M11 = {  czf * cyf,  szf * cyf };

    float cb_, sb_, p0r, p0i, p1r, p1i, q1r, q1i;
    {
        const int g = ln < 48 ? ln : 0;
        const float* th = thetas + g * 3;
        const float h0 = 0.5f * th[0], h1 = 0.5f * th[1], h2 = 0.5f * th[2];
        const float c0 = cosf(h0), s0 = sinf(h0);
        const float c1 = cosf(h1), s1 = sinf(h1);
        const float c2 = cosf(h2), s2 = sinf(h2);
        const c32 z0 = { c1, -s1 }, z1 = { c1, s1 };
        const c32 X00 = { c0, 0.f }, X01 = { 0.f, -s0 };
        const c32 A00 = cmul(z0, X00), A01 = cmul(z0, X01);
        const c32 A10 = cmul(z1, X01), A11 = cmul(z1, X00);
        const c32 Y00 = { c2, 0.f }, Y01 = { 0.f, -s2 };
        const c32 U00 = { Y00.r*A00.r - Y00.i*A00.i + Y01.r*A10.r - Y01.i*A10.i,
                          Y00.r*A00.i + Y00.i*A00.r + Y01.r*A10.i + Y01.i*A10.r };
        const c32 U01 = { Y00.r*A01.r - Y00.i*A01.i + Y01.r*A11.r - Y01.i*A11.i,
                          Y00.r*A01.i + Y00.i*A01.r + Y01.r*A11.i + Y01.i*A11.r };
        const c32 U10 = { Y01.r*A00.r - Y01.i*A00.i + Y00.r*A10.r - Y00.i*A10.i,
                          Y01.r*A00.i + Y01.i*A00.r + Y00.r*A10.i + Y00.i*A10.r };
        const c32 U11 = { Y01.r*A01.r - Y01.i*A01.i + Y00.r*A11.r - Y00.i*A11.i,
                          Y01.r*A01.i + Y01.i*A01.r + Y00.r*A11.i + Y00.i*A11.r };
        const c32 V00 = { U00.r*M00.r - U00.i*M00.i + U01.r*M10.r - U01.i*M10.i,
                          U00.r*M00.i + U00.i*M00.r + U01.r*M10.i + U01.i*M10.r };
        const c32 V01 = { U00.r*M01.r - U00.i*M01.i + U01.r*M11.r - U01.i*M11.i,
                          U00.r*M01.i + U00.i*M01.r + U01.r*M11.i + U01.i*M11.r };
        const c32 V10 = { U10.r*M00.r - U10.i*M00.i + U11.r*M10.r - U11.i*M10.i,
                          U10.r*M00.i + U10.i*M00.r + U11.r*M10.i + U11.i*M10.r };
        const c32 V11 = { U10.r*M01.r - U10.i*M01.i + U11.r*M11.r - U11.i*M11.i,
                          U10.r*M01.i + U10.i*M01.r + U11.r*M11.i + U11.i*M11.r };

        float cb = sqrtf(V00.r*V00.r + V00.i*V00.i);
        float sb = sqrtf(V10.r*V10.r + V10.i*V10.i);
        c32 p0, p1, q1;
        const float eps = 1e-6f;
        if (sb <= eps) {
            const float icb = 1.f / cb;
            p0 = { V00.r*icb, V00.i*icb };
            p1 = { V11.r*icb, V11.i*icb };
            q1 = { 1.f, 0.f };
            cb = 1.f; sb = 0.f;
        } else if (cb <= eps) {
            const float isb = 1.f / sb;
            p1 = { V10.r*isb, V10.i*isb };
            p0 = { -V01.r*isb, -V01.i*isb };
            q1 = { 1.f, 0.f };
            cb = 0.f; sb = 1.f;
        } else {
            const float icb = 1.f / cb, isb = 1.f / sb;
            p0 = { V00.r*icb, V00.i*icb };
            p1 = { V10.r*isb, V10.i*isb };
            const c32 t = { V11.r*p1.r + V11.i*p1.i, V11.i*p1.r - V11.r*p1.i };
            q1 = { t.r*icb, t.i*icb };
        }
        cb_ = cb; sb_ = sb;
        p0r = p0.r; p0i = p0.i; p1r = p1.r; p1i = p1.i; q1r = q1.r; q1i = q1.i;
    }
    // column-0 entries for layer 0
    const float a0r = p0r * cb_, a0i = p0i * cb_;
    const float a1r = p1r * sb_, a1i = p1i * sb_;

    // ---- cross-lane boundary tables (wave-local registers, no LDS) ----
    // Tb: lane = (K-1)*32 + sg*16 + j
    float TbR, TbI;
    {
        const int K12 = 12 + ((ln >> 5) ? 12 : 0);
        const int sg = (ln >> 4) & 1, j = ln & 15;
        c32 acc = { 1.f, 0.f };
        #pragma unroll
        for (int m = 3; m >= 0; --m) {
            const int gl = K12 + (11 - m);
            const float P0r = shf(p0r, gl), P0i = shf(p0i, gl);
            const float P1r = shf(p1r, gl), P1i = shf(p1i, gl);
            const bool bm = (j >> m) & 1;
            acc = cmul(acc, c32{ bm ? P1r : P0r, bm ? P1i : P0i });
            const float Qr = shf(q1r, gl + 12), Qi = shf(q1i, gl + 12);
            const bool qc = ((sg ^ __popc(j >> m)) & 1) != 0;
            acc = cmul(acc, c32{ qc ? Qr : 1.f, qc ? Qi : 0.f });
        }
        TbR = acc.r; TbI = acc.i;
    }
    // CHi: lane = (K-1)*16 + h   (valid in lanes 0..31)
    float CHiR, CHiI;
    {
        const int Kh12 = 12 + (((ln >> 4) & 1) ? 12 : 0);
        const int h = ln & 15;
        c32 acc = { 1.f, 0.f };
        #pragma unroll
        for (int Q = 0; Q < 4; ++Q) {
            const int gl = Kh12 + Q;
            const float P0r = shf(p0r, gl), P0i = shf(p0i, gl);
            const float P1r = shf(p1r, gl), P1i = shf(p1i, gl);
            const bool bm = (h >> (3 - Q)) & 1;
            acc = cmul(acc, c32{ bm ? P1r : P0r, bm ? P1i : P0i });
            const float Qr = shf(q1r, gl + 12), Qi = shf(q1i, gl + 12);
            const bool qc = (__popc(h >> (3 - Q)) & 1) != 0;
            acc = cmul(acc, c32{ qc ? Qr : 1.f, qc ? Qi : 0.f });
        }
        CHiR = acc.r; CHiI = acc.i;
    }
    // CLo: lane = (K-1)*32 + sh*16 + lo
    float CLoR, CLoI;
    {
        const int K12 = 12 + ((ln >> 5) ? 12 : 0);
        const int sh = (ln >> 4) & 1, lo = ln & 15;
        c32 acc = { 1.f, 0.f };
        #pragma unroll
        for (int Q = 4; Q < 8; ++Q) {
            const int gl = K12 + Q;
            const float P0r = shf(p0r, gl), P0i = shf(p0i, gl);
            const float P1r = shf(p1r, gl), P1i = shf(p1i, gl);
            const bool bm = (lo >> (7 - Q)) & 1;
            acc = cmul(acc, c32{ bm ? P1r : P0r, bm ? P1i : P0i });
            const float Qr = shf(q1r, gl + 12), Qi = shf(q1i, gl + 12);
            const bool qc = ((sh ^ __popc(lo >> (7 - Q))) & 1) != 0;
            acc = cmul(acc, c32{ qc ? Qr : 1.f, qc ? Qi : 0.f });
        }
        CLoR = acc.r; CLoI = acc.i;
    }

    // ---- layer 0: tensor product (col-0 factors) with Q(1) folded in ----
    {
        const int sg0 = __popc(tid) & 1;
        c32 C = { 1.f, 0.f };
        #pragma unroll
        for (int q = 0; q < 8; ++q) {
            const float E0r = rlf(a0r, q), E0i = rlf(a0i, q);
            const float E1r = rlf(a1r, q), E1i = rlf(a1i, q);
            const bool bit = (tid >> (7 - q)) & 1;
            C = cmul(C, c32{ bit ? E1r : E0r, bit ? E1i : E0i });
            const float Qr = rlf(q1r, 12 + q), Qi = rlf(q1i, 12 + q);
            const bool qb = (__popc(tid >> (7 - q)) & 1) != 0;
            C = cmul(C, c32{ qb ? Qr : 1.f, qb ? Qi : 0.f });
        }
        c32 pf0[4], pf1[4], qv[4];
        #pragma unroll
        for (int m = 0; m < 4; ++m) {
            const int Q = 11 - m;
            pf0[m] = { rlf(a0r, Q), rlf(a0i, Q) };
            pf1[m] = { rlf(a1r, Q), rlf(a1i, Q) };
            qv[m]  = { rlf(q1r, 12 + Q), rlf(q1i, 12 + Q) };
        }
        c32 T[16];
        diagTree(T, C, pf0, pf1, qv, sg0);
        const int beta = Cm(tid << 4);
        #pragma unroll
        for (int m = 0; m < 8; ++m)
            a4[(beta ^ (2 * m)) >> 1] =
                make_float4(T[2*m].r, T[2*m].i, T[2*m+1].r, T[2*m+1].i);
    }
    __syncthreads();

    // ---- layers 1..3: RY passes + boundary diag at pass 2 ----
    const int Lo = tid & 15, Hh = tid >> 4;

    #define RUN_LAYER(K)                                                            \
    {                                                                               \
        /* pass 0: qubits 0-3 (t bits 11-8) */                                      \
        {                                                                           \
            const float c0 = rlf(cb_, K*12+0), s0 = rlf(sb_, K*12+0);               \
            const float c1 = rlf(cb_, K*12+1), s1 = rlf(sb_, K*12+1);               \
            const float c2 = rlf(cb_, K*12+2), s2 = rlf(sb_, K*12+2);               \
            const float c3 = rlf(cb_, K*12+3), s3 = rlf(sb_, K*12+3);               \
            const int beta = Cm(G(tid, K));                                         \
            c32 v[16];                                                              \
            _Pragma("unroll")                                                       \
            for (int j = 0; j < 16; ++j) {                                          \
                const float2 t = amp[beta ^ Cm(G(j << 8, K))];                      \
                v[j] = { t.x, t.y };                                                \
            }                                                                       \
            applyRY<3>(v, c0, s0); applyRY<2>(v, c1, s1);                           \
            applyRY<1>(v, c2, s2); applyRY<0>(v, c3, s3);                           \
            _Pragma("unroll")                                                       \
            for (int j = 0; j < 16; ++j)                                            \
                amp[beta ^ Cm(G(j << 8, K))] = make_float2(v[j].r, v[j].i);         \
            __syncthreads();                                                        \
        }                                                                           \
        /* pass 1: qubits 4-7 (t bits 7-4) */                                       \
        {                                                                           \
            const float c0 = rlf(cb_, K*12+4), s0 = rlf(sb_, K*12+4);               \
            const float c1 = rlf(cb_, K*12+5), s1 = rlf(sb_, K*12+5);               \
            const float c2 = rlf(cb_, K*12+6), s2 = rlf(sb_, K*12+6);               \
            const float c3 = rlf(cb_, K*12+7), s3 = rlf(sb_, K*12+7);               \
            const int beta = Cm(G((Hh << 8) | Lo, K));                              \
            c32 v[16];                                                              \
            _Pragma("unroll")                                                       \
            for (int j = 0; j < 16; ++j) {                                          \
                const float2 t = amp[beta ^ Cm(G(j << 4, K))];                      \
                v[j] = { t.x, t.y };                                                \
            }                                                                       \
            applyRY<3>(v, c0, s0); applyRY<2>(v, c1, s1);                           \
            applyRY<1>(v, c2, s2); applyRY<0>(v, c3, s3);                           \
            _Pragma("unroll")                                                       \
            for (int j = 0; j < 16; ++j)                                            \
                amp[beta ^ Cm(G(j << 4, K))] = make_float2(v[j].r, v[j].i);         \
            __syncthreads();                                                        \
        }                                                                           \
        /* pass 2: qubits 8-11 (t bits 3-0), b128; boundary diag before write */    \
        {                                                                           \
            const float c0 = rlf(cb_, K*12+8),  s0 = rlf(sb_, K*12+8);              \
            const float c1 = rlf(cb_, K*12+9),  s1 = rlf(sb_, K*12+9);              \
            const float c2 = rlf(cb_, K*12+10), s2 = rlf(sb_, K*12+10);             \
            const float c3 = rlf(cb_, K*12+11), s3 = rlf(sb_, K*12+11);             \
            const int beta = Cm(G((Hh << 8) | (Lo << 4), K));                       \
            c32 v[16];                                                              \
            _Pragma("unroll")                                                       \
            for (int m = 0; m < 8; ++m) {                                           \
                const int gg = Cm(G(2 * m, K));                                     \
                const float4 F = a4[(beta ^ (gg & ~1)) >> 1];                       \
                const c32 flo = { F.x, F.y }, fhi = { F.z, F.w };                   \
                if (gg & 1) { v[2*m+1] = flo; v[2*m] = fhi; }                       \
                else        { v[2*m] = flo;   v[2*m+1] = fhi; }                     \
            }                                                                       \
            applyRY<3>(v, c0, s0); applyRY<2>(v, c1, s1);                           \
            applyRY<1>(v, c2, s2); applyRY<0>(v, c3, s3);                           \
            if constexpr (K < 3) {                                                  \
                const int sgm = __popc(tid) & 1;                                    \
                const int sgh = __popc(tid >> 4) & 1;                               \
                const float chR = shf(CHiR, (K-1)*16 + Hh);                         \
                const float chI = shf(CHiI, (K-1)*16 + Hh);                         \
                const float clR = shf(CLoR, (K-1)*32 + sgh*16 + Lo);                \
                const float clI = shf(CLoI, (K-1)*32 + sgh*16 + Lo);                \
                const c32 CT = cmul(c32{chR, chI}, c32{clR, clI});                  \
                const int tbb = (K-1)*32 + sgm*16;                                  \
                _Pragma("unroll")                                                   \
                for (int j = 0; j < 16; ++j) {                                      \
                    const float tr = shf(TbR, tbb + j), ti = shf(TbI, tbb + j);     \
                    v[j] = cmul(v[j], cmul(CT, c32{tr, ti}));                       \
                }                                                                   \
            }                                                                       \
            _Pragma("unroll")                                                       \
            for (int m = 0; m < 8; ++m) {                                           \
                const int gg = Cm(G(2 * m, K));                                     \
                float4 F;                                                           \
                if (gg & 1) F = make_float4(v[2*m+1].r, v[2*m+1].i, v[2*m].r,   v[2*m].i); \
                else        F = make_float4(v[2*m].r,   v[2*m].i,   v[2*m+1].r, v[2*m+1].i); \
                a4[(beta ^ (gg & ~1)) >> 1] = F;                                    \
            }                                                                       \
            __syncthreads();                                                        \
        }                                                                           \
    }

    RUN_LAYER(1)
    RUN_LAYER(2)
    RUN_LAYER(3)
    #undef RUN_LAYER

    // ---- readout: weight = parity(MASKE & e); P(3) dropped (pure phase) ----
    float acc = 0.f;
    #pragma unroll
    for (int it = 0; it < 8; ++it) {
        const int pe = (it << 9) | (tid << 1);
        const float4 F = a4[pe >> 1];
        const float m0 = fmaf(F.x, F.x, F.y * F.y);
        const float m1 = fmaf(F.z, F.z, F.w * F.w);
        acc += (__popc(pe & MASKE) & 1) ? -m0 : m0;
        acc += (__popc((pe | 1) & MASKE) & 1) ? -m1 : m1;
    }
    #pragma unroll
    for (int off = 32; off > 0; off >>= 1) acc += __shfl_down(acc, off, 64);
    __syncthreads();                       // all amp reads complete
    if (ln == 0) amp[tid >> 6] = make_float2(acc, 0.f);
    __syncthreads();
    if (tid == 0) out[b] = amp[0].x + amp[1].x + amp[2].x + amp[3].x;
}

} // namespace

extern "C" void kernel_launch(void* const* d_in, const int* in_sizes, int n_in,
                              void* d_out, int out_size, void* d_ws, size_t ws_size,
                              hipStream_t stream) {
    const float* x      = (const float*)d_in[0];
    const float* thetas = (const float*)d_in[1];
    float* out          = (float*)d_out;
    const int batch = in_sizes[0];
    qcirc_kernel<<<batch, THREADS, 0, stream>>>(x, thetas, out);
}